// Round 1
// baseline (766.882 us; speedup 1.0000x reference)
//
#include <hip/hip_runtime.h>
#include <math.h>

#define NN   6144
#define HID  48
#define BLK  512
// sqrt(6144)
#define SCALE 78.38367176906175f

// ---------------- K1: QKV projections -------------------------------------
// q/k/v[head][j][d] layouts in workspace, fp32. y = h @ W^T + b
__global__ __launch_bounds__(256)
void qkv_kernel(const float* __restrict__ h,
                const float* __restrict__ Wq, const float* __restrict__ bq,
                const float* __restrict__ Wk, const float* __restrict__ bk,
                const float* __restrict__ Wv, const float* __restrict__ bv,
                float* __restrict__ qw, float* __restrict__ kw, float* __restrict__ vw) {
    __shared__ float sW[3 * HID * HID + 3 * HID];
    for (int t = threadIdx.x; t < 3 * HID * HID; t += blockDim.x) {
        int m = t / (HID * HID), r = t % (HID * HID);
        const float* W = (m == 0) ? Wq : ((m == 1) ? Wk : Wv);
        sW[t] = W[r];
    }
    if (threadIdx.x < 3 * HID) {
        int m = threadIdx.x / HID, r = threadIdx.x % HID;
        const float* b = (m == 0) ? bq : ((m == 1) ? bk : bv);
        sW[3 * HID * HID + threadIdx.x] = b[r];
    }
    __syncthreads();
    int idx = blockIdx.x * blockDim.x + threadIdx.x;  // over N*HID exactly
    int i = idx / HID, c = idx % HID;
    const float* hrow = h + (size_t)i * HID;
    float aq = 0.f, ak = 0.f, av = 0.f;
    #pragma unroll 8
    for (int x = 0; x < HID; ++x) {
        float hv = hrow[x];
        aq = fmaf(hv, sW[0 * HID * HID + c * HID + x], aq);
        ak = fmaf(hv, sW[1 * HID * HID + c * HID + x], ak);
        av = fmaf(hv, sW[2 * HID * HID + c * HID + x], av);
    }
    aq += sW[3 * HID * HID + c];
    ak += sW[3 * HID * HID + HID + c];
    av += sW[3 * HID * HID + 2 * HID + c];
    int head = c >> 4, d = c & 15;
    size_t off = ((size_t)head * NN + i) * 16 + d;
    qw[off] = aq; kw[off] = ak; vw[off] = av;
}

// ---------------- K1b: V_total[c] = sum_j v[h][j][d] ----------------------
__global__ __launch_bounds__(256)
void vtot_kernel(const float* __restrict__ vw, float* __restrict__ vtot) {
    int c = blockIdx.x;            // 0..47
    int head = c >> 4, d = c & 15;
    float s = 0.f;
    for (int j = threadIdx.x; j < NN; j += 256)
        s += vw[((size_t)head * NN + j) * 16 + d];
    #pragma unroll
    for (int o = 32; o; o >>= 1) s += __shfl_xor(s, o, 64);
    __shared__ float red[4];
    int wid = threadIdx.x >> 6, lane = threadIdx.x & 63;
    if (lane == 0) red[wid] = s;
    __syncthreads();
    if (threadIdx.x == 0) vtot[c] = red[0] + red[1] + red[2] + red[3];
}

// ---------------- K2: masked attention row kernel -------------------------
// One block per row i; 3 heads. Score row held in registers:
// thread owns j in {4*(tid+c*BLK) .. +3} for c=0..2.
__global__ __launch_bounds__(BLK, 4)
void attn_kernel(const float* __restrict__ A,
                 const float* __restrict__ qw, const float* __restrict__ kw,
                 const float* __restrict__ vw, const float* __restrict__ vtot,
                 float* __restrict__ out) {
    __shared__ float red[256 * 48];   // 48 KB: final out reduction
    __shared__ float ssc[32];         // per-wave partials
    const int i = blockIdx.x;
    const int tid = threadIdx.x;
    const int wid = tid >> 6, lane = tid & 63;

    // q for row i, 3 heads (uniform across threads)
    float4 qreg[3][4];
    #pragma unroll
    for (int hh = 0; hh < 3; ++hh) {
        const float4* qp = (const float4*)(qw + ((size_t)hh * NN + i) * 16);
        #pragma unroll
        for (int r = 0; r < 4; ++r) qreg[hh][r] = qp[r];
    }

    // ---- Phase A: scores into registers, track max (zeros included) ----
    const float4* Arow = (const float4*)(A + (size_t)i * NN);
    float4 sreg[3][3];
    float m0 = -INFINITY, m1 = -INFINITY, m2 = -INFINITY;
    #pragma unroll
    for (int c = 0; c < 3; ++c) {
        int t = tid + c * BLK;
        float4 a4 = Arow[t];
        float ae[4] = {a4.x, a4.y, a4.z, a4.w};
        float sv[3][4];
        #pragma unroll
        for (int e = 0; e < 4; ++e) {
            sv[0][e] = 0.f; sv[1][e] = 0.f; sv[2][e] = 0.f;
            float a = ae[e];
            if (a != 0.f) {
                int j = 4 * t + e;
                #pragma unroll
                for (int hh = 0; hh < 3; ++hh) {
                    const float4* kp = (const float4*)(kw + ((size_t)hh * NN + j) * 16);
                    float dot = 0.f;
                    #pragma unroll
                    for (int r = 0; r < 4; ++r) {
                        float4 kv = kp[r];
                        dot = fmaf(qreg[hh][r].x, kv.x, dot);
                        dot = fmaf(qreg[hh][r].y, kv.y, dot);
                        dot = fmaf(qreg[hh][r].z, kv.z, dot);
                        dot = fmaf(qreg[hh][r].w, kv.w, dot);
                    }
                    sv[hh][e] = dot * a * SCALE;
                }
            }
            m0 = fmaxf(m0, sv[0][e]);
            m1 = fmaxf(m1, sv[1][e]);
            m2 = fmaxf(m2, sv[2][e]);
        }
        #pragma unroll
        for (int hh = 0; hh < 3; ++hh)
            sreg[hh][c] = make_float4(sv[hh][0], sv[hh][1], sv[hh][2], sv[hh][3]);
    }

    // ---- block-reduce max (3 heads) ----
    #pragma unroll
    for (int o = 32; o; o >>= 1) {
        m0 = fmaxf(m0, __shfl_xor(m0, o, 64));
        m1 = fmaxf(m1, __shfl_xor(m1, o, 64));
        m2 = fmaxf(m2, __shfl_xor(m2, o, 64));
    }
    if (lane == 0) { ssc[wid] = m0; ssc[8 + wid] = m1; ssc[16 + wid] = m2; }
    __syncthreads();
    float M[3];
    #pragma unroll
    for (int hh = 0; hh < 3; ++hh) {
        float mm = ssc[hh * 8];
        #pragma unroll
        for (int w2 = 1; w2 < 8; ++w2) mm = fmaxf(mm, ssc[hh * 8 + w2]);
        M[hh] = mm;
    }
    __syncthreads();  // ssc reused below

    // ---- Phase B: exp in place, sum l.  masked (s==0) -> z exactly ----
    float z[3] = {__expf(-M[0]), __expf(-M[1]), __expf(-M[2])};
    float l0 = 0.f, l1 = 0.f, l2 = 0.f;
    #pragma unroll
    for (int c = 0; c < 3; ++c) {
        #pragma unroll
        for (int hh = 0; hh < 3; ++hh) {
            float4 s4 = sreg[hh][c];
            float4 p;
            p.x = (s4.x == 0.f) ? z[hh] : __expf(s4.x - M[hh]);
            p.y = (s4.y == 0.f) ? z[hh] : __expf(s4.y - M[hh]);
            p.z = (s4.z == 0.f) ? z[hh] : __expf(s4.z - M[hh]);
            p.w = (s4.w == 0.f) ? z[hh] : __expf(s4.w - M[hh]);
            sreg[hh][c] = p;
            float ps = (p.x + p.y) + (p.z + p.w);
            if (hh == 0) l0 += ps; else if (hh == 1) l1 += ps; else l2 += ps;
        }
    }
    #pragma unroll
    for (int o = 32; o; o >>= 1) {
        l0 += __shfl_xor(l0, o, 64);
        l1 += __shfl_xor(l1, o, 64);
        l2 += __shfl_xor(l2, o, 64);
    }
    if (lane == 0) { ssc[wid] = l0; ssc[8 + wid] = l1; ssc[16 + wid] = l2; }
    __syncthreads();
    float inv[3];
    #pragma unroll
    for (int hh = 0; hh < 3; ++hh) {
        float ls = 0.f;
        #pragma unroll
        for (int w2 = 0; w2 < 8; ++w2) ls += ssc[hh * 8 + w2];
        inv[hh] = 1.0f / ls;
    }

    // ---- Phase C: write normalized scores + sparse out accumulation ----
    float acc[48];
    #pragma unroll
    for (int c2 = 0; c2 < 48; ++c2) acc[c2] = 0.f;
    float* Pout = out + (size_t)NN * HID + (size_t)i * NN;
    #pragma unroll
    for (int c = 0; c < 3; ++c) {
        int t = tid + c * BLK;
        #pragma unroll
        for (int hh = 0; hh < 3; ++hh) {
            float4 p = sreg[hh][c];
            float4 P = make_float4(p.x * inv[hh], p.y * inv[hh], p.z * inv[hh], p.w * inv[hh]);
            ((float4*)(Pout + (size_t)hh * NN * NN))[t] = P;
            float pe[4] = {p.x, p.y, p.z, p.w};
            #pragma unroll
            for (int e = 0; e < 4; ++e) {
                float w = pe[e] - z[hh];
                if (w != 0.f) {
                    int j = 4 * t + e;
                    const float4* vp = (const float4*)(vw + ((size_t)hh * NN + j) * 16);
                    #pragma unroll
                    for (int r = 0; r < 4; ++r) {
                        float4 vv = vp[r];
                        acc[hh * 16 + 4 * r + 0] = fmaf(w, vv.x, acc[hh * 16 + 4 * r + 0]);
                        acc[hh * 16 + 4 * r + 1] = fmaf(w, vv.y, acc[hh * 16 + 4 * r + 1]);
                        acc[hh * 16 + 4 * r + 2] = fmaf(w, vv.z, acc[hh * 16 + 4 * r + 2]);
                        acc[hh * 16 + 4 * r + 3] = fmaf(w, vv.w, acc[hh * 16 + 4 * r + 3]);
                    }
                }
            }
        }
    }

    // ---- reduce acc[48] over 512 threads via LDS ----
    if (tid < 256) {
        #pragma unroll
        for (int r = 0; r < 12; ++r)
            ((float4*)(red + (size_t)tid * 48))[r] =
                make_float4(acc[4 * r], acc[4 * r + 1], acc[4 * r + 2], acc[4 * r + 3]);
    }
    __syncthreads();
    if (tid >= 256) {
        int row = tid - 256;
        #pragma unroll
        for (int c2 = 0; c2 < 48; ++c2) red[row * 48 + c2] += acc[c2];
    }
    __syncthreads();
    for (int st = 128; st >= 16; st >>= 1) {
        for (int t2 = tid; t2 < st * 48; t2 += BLK) {
            int row = t2 / 48, c2 = t2 % 48;
            red[row * 48 + c2] += red[(row + st) * 48 + c2];
        }
        __syncthreads();
    }
    if (tid < 48) {
        float ssum = 0.f;
        #pragma unroll
        for (int r = 0; r < 16; ++r) ssum += red[r * 48 + tid];
        int hh = tid >> 4;
        out[(size_t)i * HID + tid] = (ssum + z[hh] * vtot[tid]) * inv[hh];
    }
}

// ---------------- launch ---------------------------------------------------
extern "C" void kernel_launch(void* const* d_in, const int* in_sizes, int n_in,
                              void* d_out, int out_size, void* d_ws, size_t ws_size,
                              hipStream_t stream) {
    const float* A  = (const float*)d_in[0];
    const float* h  = (const float*)d_in[1];
    const float* Wq = (const float*)d_in[2];
    const float* bq = (const float*)d_in[3];
    const float* Wk = (const float*)d_in[4];
    const float* bk = (const float*)d_in[5];
    const float* Wv = (const float*)d_in[6];
    const float* bv = (const float*)d_in[7];
    float* out = (float*)d_out;
    float* ws  = (float*)d_ws;

    float* qw   = ws;                       // 3*N*16
    float* kw   = ws + (size_t)3 * NN * 16;
    float* vw   = ws + (size_t)6 * NN * 16;
    float* vtot = ws + (size_t)9 * NN * 16; // 48 floats

    qkv_kernel<<<(NN * HID) / 256, 256, 0, stream>>>(h, Wq, bq, Wk, bk, Wv, bv, qw, kw, vw);
    vtot_kernel<<<HID, 256, 0, stream>>>(vw, vtot);
    attn_kernel<<<NN, BLK, 0, stream>>>(A, qw, kw, vw, vtot, out);
}